// Round 20
// baseline (90.002 us; speedup 1.0000x reference)
//
#include <hip/hip_runtime.h>
#include <math.h>

#define TSEQ 2048
#define NB   2
#define DM   1024
#define NH   16
#define DH   64
#define GN_EPS 1e-5f

typedef short v8s __attribute__((ext_vector_type(8)));
typedef short v4s __attribute__((ext_vector_type(4)));
typedef float v4f __attribute__((ext_vector_type(4)));

__device__ __forceinline__ short f2bf(float f) {
    union { float f; unsigned u; } c; c.f = f;
    unsigned u = c.u;
    unsigned r = (u + 0x7fffu + ((u >> 16) & 1u)) >> 16;   // RNE
    return (short)r;
}
__device__ __forceinline__ float bf2f(short s) {
    union { unsigned u; float f; } c; c.u = ((unsigned)(unsigned short)s) << 16;
    return c.f;
}

// pack two f32 -> two bf16 in one instruction (no builtin on gfx950)
__device__ __forceinline__ unsigned cvtpk_bf16(float lo, float hi) {
    unsigned r;
    asm("v_cvt_pk_bf16_f32 %0, %1, %2" : "=v"(r) : "v"(lo), "v"(hi));
    return r;
}

// async global->LDS, 16B per lane.  LDS dest = wave-uniform base + lane*16.
__device__ __forceinline__ void gl_lds16(const void* g, void* l) {
    __builtin_amdgcn_global_load_lds(
        (const __attribute__((address_space(1))) void*)g,
        (__attribute__((address_space(3))) void*)l, 16, 0, 0);
}

// ---------------------------------------------------------------------------
// cast x and the 4 weight matrices to bf16
// ---------------------------------------------------------------------------
__global__ __launch_bounds__(256) void cast_kernel(
    const float* __restrict__ x,
    const float* __restrict__ Wq, const float* __restrict__ Wk,
    const float* __restrict__ Wv, const float* __restrict__ Wo,
    short* __restrict__ xbf, short* __restrict__ wbf)
{
    const int NX = NB * TSEQ * DM;            // 4,194,304
    const int NW = DM * DM;                   // 1,048,576
    const int total4 = (NX + 4 * NW) / 4;     // 2,097,152
    for (int i = blockIdx.x * 256 + threadIdx.x; i < total4;
         i += gridDim.x * 256) {
        int e = i * 4;
        const float* src; short* dst;
        if (e < NX) { src = x + e; dst = xbf + e; }
        else {
            int o = e - NX;
            int w = o >> 20;
            int r = o & (NW - 1);
            src = (w == 0 ? Wq : w == 1 ? Wk : w == 2 ? Wv : Wo) + r;
            dst = wbf + o;
        }
        v4f v = *(const v4f*)src;
        v4s s;
        #pragma unroll
        for (int j = 0; j < 4; ++j) s[j] = f2bf(v[j]);
        *(v4s*)dst = s;
    }
}

// ---------------------------------------------------------------------------
// FUSED QKV projection, HIGH-OCCUPANCY variant: 64m x 64n tile, BK=64.
// LDS = A(8KB) + Bq,Bk,Bv(8KB each) = 32 KB -> 5 blocks/CU; VGPR ~<=100
// (launch_bounds(256,4)) -> 20 waves/CU.  Per K-step: stage 8x16B/thread,
// ONE vmcnt(0)+barrier, 24 MFMA/wave (A reused 3x).  grid 1024, XCD
// swizzle 4m x 2n.  BN=64 = one head -> decay l2g block-uniform.
// Q uses SWAPPED operands (packed row-major stores); K/V normal.
// ---------------------------------------------------------------------------
__global__ __launch_bounds__(256, 4) void gemm_qkv_fused(
    const short* __restrict__ xbf, const short* __restrict__ wbf,
    short* __restrict__ Qb, short* __restrict__ Kb,
    short* __restrict__ Kt, short* __restrict__ Vt)
{
    const int bid = blockIdx.x;                 // 0..1023
    const int xcd = bid & 7, ch = bid >> 3;     // 128 blocks per XCD
    const int xm = xcd >> 1, xn = xcd & 1;      // 4m x 2n XCD sub-grids
    const int mt = xm * 16 + (ch >> 3);         // 64 m-tiles
    const int nt = xn * 8 + (ch & 7);           // 16 n-tiles
    const int m0 = mt * 64, n0 = nt * 64;

    const int t = threadIdx.x, l = t & 63, w = t >> 6;
    const int wm = (w >> 1) * 32, wn = (w & 1) * 32;
    const int lr = l & 15, g = l >> 4;
    const int swz = (lr & 7) << 4;

    __shared__ short As[64 * 64];               // 8 KB
    __shared__ short Bs[3][64 * 64];            // 24 KB

    v4f acc[3][2][2];
    #pragma unroll
    for (int z = 0; z < 3; ++z)
        #pragma unroll
        for (int i = 0; i < 2; ++i)
            #pragma unroll
            for (int j = 0; j < 2; ++j) acc[z][i][j] = (v4f){0.f,0.f,0.f,0.f};

    const char* Agp = (const char*)(xbf + (size_t)m0 * DM);
    const char* Bgp = (const char*)(wbf + (size_t)n0 * DM);
    const size_t ZS = (size_t)DM * DM * 2;      // 2 MiB per weight matrix

    int soff[2], sdst[2];
    #pragma unroll
    for (int p = 0; p < 2; ++p) {
        int c = p * 256 + t;
        int row = c >> 3, u = c & 7;            // row 0..63
        soff[p] = row * (DM * 2) + ((u * 16) ^ ((row & 7) << 4));
        sdst[p] = (p * 256 + (t & 192)) * 16;
    }

    for (int kt = 0; kt < DM / 64; ++kt) {
        const int kb = kt * 128;
        #pragma unroll
        for (int p = 0; p < 2; ++p)
            gl_lds16(Agp + (size_t)soff[p] + kb, (char*)As + sdst[p]);
        #pragma unroll
        for (int z = 0; z < 3; ++z)
            #pragma unroll
            for (int p = 0; p < 2; ++p)
                gl_lds16(Bgp + ZS * z + (size_t)soff[p] + kb,
                         (char*)Bs[z] + sdst[p]);
        asm volatile("s_waitcnt vmcnt(0)" ::: "memory");
        __syncthreads();

        v8s af[2][2];
        #pragma unroll
        for (int i = 0; i < 2; ++i) {
            int rowa = wm + i * 16 + lr;
            af[i][0] = *(const v8s*)((const char*)As + rowa * 128 + ((g * 16) ^ swz));
            af[i][1] = *(const v8s*)((const char*)As + rowa * 128 + ((64 + g * 16) ^ swz));
        }
        #pragma unroll
        for (int z = 0; z < 3; ++z) {
            #pragma unroll
            for (int j = 0; j < 2; ++j) {
                int rowb = wn + j * 16 + lr;
                v8s b0 = *(const v8s*)((const char*)Bs[z] + rowb * 128 + ((g * 16) ^ swz));
                v8s b1 = *(const v8s*)((const char*)Bs[z] + rowb * 128 + ((64 + g * 16) ^ swz));
                #pragma unroll
                for (int i = 0; i < 2; ++i) {
                    if (z == 0) {   // Q: swapped -> transposed fragment
                        acc[0][i][j] = __builtin_amdgcn_mfma_f32_16x16x32_bf16(
                            b0, af[i][0], acc[0][i][j], 0, 0, 0);
                        acc[0][i][j] = __builtin_amdgcn_mfma_f32_16x16x32_bf16(
                            b1, af[i][1], acc[0][i][j], 0, 0, 0);
                    } else {
                        acc[z][i][j] = __builtin_amdgcn_mfma_f32_16x16x32_bf16(
                            af[i][0], b0, acc[z][i][j], 0, 0, 0);
                        acc[z][i][j] = __builtin_amdgcn_mfma_f32_16x16x32_bf16(
                            af[i][1], b1, acc[z][i][j], 0, 0, 0);
                    }
                }
            }
        }
        __syncthreads();
    }

    // ---------------- epilogues (one head: l2g block-uniform) ----------------
    const int head = n0 >> 6;
    const float l2g = log2f(1.0f - exp2f(-5.0f - (float)head));

    // Q: packed v4s row-major stores, 2 exp2/thread
    {
        float fac[2];
        #pragma unroll
        for (int i = 0; i < 2; ++i) {
            int tl = (m0 + wm + i * 16 + lr) & 63;
            fac[i] = exp2f(fmaf(l2g, (float)tl, -3.0f));   // gamma^tl / 8
        }
        #pragma unroll
        for (int i = 0; i < 2; ++i) {
            int mrow = m0 + wm + i * 16 + lr;
            #pragma unroll
            for (int j = 0; j < 2; ++j) {
                int ncol = n0 + wn + j * 16 + g * 4;
                v4s pk;
                #pragma unroll
                for (int r = 0; r < 4; ++r) pk[r] = f2bf(acc[0][i][j][r] * fac[i]);
                *(v4s*)(Qb + (size_t)mrow * DM + ncol) = pk;
            }
        }
    }
    // K: Kb row-major scalar + Kt transposed packed
    {
        const float l2gk = -l2g;
        #pragma unroll
        for (int i = 0; i < 2; ++i) {
            int row  = m0 + wm + i * 16 + g * 4;
            int bidx = row >> 11, tb = row & (TSEQ - 1);
            #pragma unroll
            for (int j = 0; j < 2; ++j) {
                int col = n0 + wn + j * 16 + lr;
                v4s pk;
                #pragma unroll
                for (int r = 0; r < 4; ++r) {
                    int tl = (row + r) & 63;
                    float fc = exp2f(l2gk * (float)tl);
                    short bv = f2bf(acc[1][i][j][r] * fc);
                    Kb[(size_t)(row + r) * DM + col] = bv;
                    pk[r] = bv;
                }
                *(v4s*)(Kt + ((size_t)bidx << 21) + ((size_t)col << 11) + tb) = pk;
            }
        }
    }
    // V: Vt transposed packed
    {
        #pragma unroll
        for (int i = 0; i < 2; ++i) {
            int row  = m0 + wm + i * 16 + g * 4;
            int bidx = row >> 11, tb = row & (TSEQ - 1);
            #pragma unroll
            for (int j = 0; j < 2; ++j) {
                int col = n0 + wn + j * 16 + lr;
                v4s pk;
                #pragma unroll
                for (int r = 0; r < 4; ++r) pk[r] = f2bf(acc[2][i][j][r]);
                *(v4s*)(Vt + ((size_t)bidx << 21) + ((size_t)col << 11) + tb) = pk;
            }
        }
    }
}

// ---------------------------------------------------------------------------
// Double-buffered staged 128x128 loop (64 KB LDS) — for the 1-block/CU
// out-GEMM where there is no TLP to lose.  SWAP=true -> transposed fragment.
// ---------------------------------------------------------------------------
template <bool SWAP>
__device__ __forceinline__ void mm_loop_db(
    const char* Agp, const char* Bgp, char* lds,
    int t, int lr, int g, int wr, int wc, v4f acc[4][4])
{
    int soff[4], sdst[4];
    #pragma unroll
    for (int p = 0; p < 4; ++p) {
        int i = p * 256 + t;
        int row = i >> 3;
        int cp  = (i & 7) * 16;
        soff[p] = row * (DM * 2) + (cp ^ ((row & 7) << 4));
        sdst[p] = (p * 256 + (t & 192)) * 16;      // wave-uniform base
    }
    const int swz = (lr & 7) << 4;

    #pragma unroll
    for (int p = 0; p < 4; ++p) {
        gl_lds16(Agp + (size_t)soff[p], lds + sdst[p]);
        gl_lds16(Bgp + (size_t)soff[p], lds + 16384 + sdst[p]);
    }

    for (int kt = 0; kt < DM / 64; ++kt) {
        const char* cur = lds + (kt & 1) * 32768;
        asm volatile("s_waitcnt vmcnt(0)" ::: "memory");
        __syncthreads();

        if (kt < DM / 64 - 1) {
            char* nxt = lds + ((kt + 1) & 1) * 32768;
            const int kb = (kt + 1) * 128;
            #pragma unroll
            for (int p = 0; p < 4; ++p) {
                gl_lds16(Agp + (size_t)soff[p] + kb, nxt + sdst[p]);
                gl_lds16(Bgp + (size_t)soff[p] + kb, nxt + 16384 + sdst[p]);
            }
        }

        v8s bfr[4][2];
        #pragma unroll
        for (int j = 0; j < 4; ++j) {
            int rowb = wc + j * 16 + lr;
            #pragma unroll
            for (int ks = 0; ks < 2; ++ks)
                bfr[j][ks] = *(const v8s*)(cur + 16384 + rowb * 128
                               + ((ks * 64 + g * 16) ^ swz));
        }
        #pragma unroll
        for (int i = 0; i < 4; ++i) {
            int rowa = wr + i * 16 + lr;
            v8s a0 = *(const v8s*)(cur + rowa * 128 + ((g * 16) ^ swz));
            v8s a1 = *(const v8s*)(cur + rowa * 128 + ((64 + g * 16) ^ swz));
            #pragma unroll
            for (int j = 0; j < 4; ++j) {
                if (SWAP) {
                    acc[i][j] = __builtin_amdgcn_mfma_f32_16x16x32_bf16(
                        bfr[j][0], a0, acc[i][j], 0, 0, 0);
                    acc[i][j] = __builtin_amdgcn_mfma_f32_16x16x32_bf16(
                        bfr[j][1], a1, acc[i][j], 0, 0, 0);
                } else {
                    acc[i][j] = __builtin_amdgcn_mfma_f32_16x16x32_bf16(
                        a0, bfr[j][0], acc[i][j], 0, 0, 0);
                    acc[i][j] = __builtin_amdgcn_mfma_f32_16x16x32_bf16(
                        a1, bfr[j][1], acc[i][j], 0, 0, 0);
                }
            }
        }
    }
}

// ---------------------------------------------------------------------------
// chunk_kv: per (b,h,chunk) compute A_c^T[dv][dk] = sum_jl V[jl][dv]*K'[jl][dk]
// ---------------------------------------------------------------------------
__global__ __launch_bounds__(256, 2) void chunk_kv(
    const short* __restrict__ Kt, const short* __restrict__ Vt,
    short* __restrict__ At)
{
    const int bid = blockIdx.x;                // 1024
    const int c = bid & 31, bh = bid >> 5;
    const int b = bh >> 4, h = bh & 15;
    const int tid = threadIdx.x, l = tid & 63, w = tid >> 6;
    const int lr = l & 15, g = l >> 4;

    const size_t rowbase = ((size_t)b * DM + h * 64);

    v8s kf[2], vf[4][2];
    {
        const short* kp = Kt + (rowbase + 16 * w + lr) * TSEQ + 64 * c;
        kf[0] = *(const v8s*)(kp + g * 8);
        kf[1] = *(const v8s*)(kp + 32 + g * 8);
    }
    #pragma unroll
    for (int j = 0; j < 4; ++j) {
        const short* vp = Vt + (rowbase + j * 16 + lr) * TSEQ + 64 * c;
        vf[j][0] = *(const v8s*)(vp + g * 8);
        vf[j][1] = *(const v8s*)(vp + 32 + g * 8);
    }

    v4f acc[4];
    #pragma unroll
    for (int j = 0; j < 4; ++j) acc[j] = (v4f){0.f, 0.f, 0.f, 0.f};

    #pragma unroll
    for (int j = 0; j < 4; ++j) {
        acc[j] = __builtin_amdgcn_mfma_f32_16x16x32_bf16(kf[0], vf[j][0], acc[j], 0, 0, 0);
        acc[j] = __builtin_amdgcn_mfma_f32_16x16x32_bf16(kf[1], vf[j][1], acc[j], 0, 0, 0);
    }

    short* Ab = At + (((size_t)bh * 32 + c) << 12);
    #pragma unroll
    for (int j = 0; j < 4; ++j) {
        v4s pk;
        #pragma unroll
        for (int r = 0; r < 4; ++r) pk[r] = f2bf(acc[j][r]);
        *(v4s*)(Ab + (j * 16 + lr) * 64 + 16 * w + g * 4) = pk;
    }
}

// ---------------------------------------------------------------------------
// chunk_scan: State_c = gamma^64 * (State_{c-1} + A_{c-1})
// ---------------------------------------------------------------------------
__global__ __launch_bounds__(256) void chunk_scan(
    const short* __restrict__ At, short* __restrict__ St)
{
    const int idx = blockIdx.x * 256 + threadIdx.x;   // 131072
    const int bh = idx >> 12;
    const int h  = bh & 15;
    const float l2g = log2f(1.0f - exp2f(-5.0f - (float)h));
    const float g64 = exp2f(l2g * 64.0f);

    const size_t base = ((size_t)bh << 17) + (idx & 4095);
    float state = 0.0f;
    #pragma unroll
    for (int c = 1; c < 32; ++c) {
        float a = bf2f(At[base + ((size_t)(c - 1) << 12)]);
        state = g64 * (state + a);
        St[base + ((size_t)c << 12)] = f2bf(state);
    }
}

// ---------------------------------------------------------------------------
// chunk_out: Y_c^T = StateT_c.Q'^T + V^T.(mask(Q'K'^T)); writes UN-NORMALIZED
// Ybf (bf16).  GN partials -> plain stores to psums (no atomics).
// ---------------------------------------------------------------------------
__global__ __launch_bounds__(256, 2) void chunk_out(
    const short* __restrict__ Qb, const short* __restrict__ Kb,
    const short* __restrict__ Vt, const short* __restrict__ St,
    short* __restrict__ Ybf, float* __restrict__ psums)
{
    const int bid = blockIdx.x;                 // 1024
    const int xcd = bid & 7, r8 = bid >> 3;
    const int bh  = xcd * 4 + (r8 >> 5);
    const int c   = r8 & 31;
    const int b = bh >> 4, h = bh & 15;
    const int tid = threadIdx.x, l = tid & 63, w = tid >> 6;
    const int lr = l & 15, g = l >> 4;

    __shared__ short strip[64 * 64];
    __shared__ float tr[64][68];
    __shared__ float red[8];

    const size_t rowQK = ((size_t)(b * TSEQ + 64 * c)) * DM + h * 64;

    v8s qf[4][2];
    #pragma unroll
    for (int j = 0; j < 4; ++j) {
        const short* qp = Qb + rowQK + (size_t)(j * 16 + lr) * DM;
        qf[j][0] = *(const v8s*)(qp + g * 8);
        qf[j][1] = *(const v8s*)(qp + 32 + g * 8);
    }
    v8s kf0, kf1;
    {
        const short* kp = Kb + rowQK + (size_t)(16 * w + lr) * DM;
        kf0 = *(const v8s*)(kp + g * 8);
        kf1 = *(const v8s*)(kp + 32 + g * 8);
    }
    v8s sf0 = {}, sf1 = {};
    if (c > 0) {
        const short* sp = St + (((size_t)bh * 32 + c) << 12) + (16 * w + lr) * 64;
        sf0 = *(const v8s*)(sp + g * 8);
        sf1 = *(const v8s*)(sp + 32 + g * 8);
    }
    v8s vf0, vf1;
    {
        const short* vp = Vt + ((size_t)(b * DM + h * 64) + 16 * w + lr) * TSEQ
                          + 64 * c;
        vf0 = *(const v8s*)(vp + g * 8);
        vf1 = *(const v8s*)(vp + 32 + g * 8);
    }

    v4f s[4];
    #pragma unroll
    for (int j = 0; j < 4; ++j) {
        v4f a = (v4f){0.f, 0.f, 0.f, 0.f};
        a = __builtin_amdgcn_mfma_f32_16x16x32_bf16(kf0, qf[j][0], a, 0, 0, 0);
        a = __builtin_amdgcn_mfma_f32_16x16x32_bf16(kf1, qf[j][1], a, 0, 0, 0);
        s[j] = a;
    }

    v4f y[4];
    #pragma unroll
    for (int j = 0; j < 4; ++j) y[j] = (v4f){0.f, 0.f, 0.f, 0.f};
    if (c > 0) {
        #pragma unroll
        for (int j = 0; j < 4; ++j) {
            y[j] = __builtin_amdgcn_mfma_f32_16x16x32_bf16(sf0, qf[j][0], y[j], 0, 0, 0);
            y[j] = __builtin_amdgcn_mfma_f32_16x16x32_bf16(sf1, qf[j][1], y[j], 0, 0, 0);
        }
    }

    #pragma unroll
    for (int j = 0; j < 4; ++j) {
        v4f vv = s[j];
        #pragma unroll
        for (int r = 0; r < 4; ++r)
            if ((j * 16 + lr) - (16 * w + g * 4 + r) < 0) vv[r] = 0.0f;
        unsigned u0 = cvtpk_bf16(vv[0], vv[1]);
        unsigned u1 = cvtpk_bf16(vv[2], vv[3]);
        int byte = ((j * 16 + lr) * 128 + 32 * w + g * 8) ^ ((lr & 7) << 4);
        *(unsigned long long*)((char*)strip + byte) =
            (unsigned long long)u0 | ((unsigned long long)u1 << 32);
    }
    __syncthreads();

    #pragma unroll
    for (int j = 0; j < 4; ++j) {
        int rb = (j * 16 + lr) * 128;
        int sw = (lr & 7) << 4;
        v8s sB0 = *(const v8s*)((char*)strip + ((rb + g * 16) ^ sw));
        v8s sB1 = *(const v8s*)((char*)strip + ((rb + 64 + g * 16) ^ sw));
        y[j] = __builtin_amdgcn_mfma_f32_16x16x32_bf16(vf0, sB0, y[j], 0, 0, 0);
        y[j] = __builtin_amdgcn_mfma_f32_16x16x32_bf16(vf1, sB1, y[j], 0, 0, 0);
    }

    float lsum = 0.f, lsq = 0.f;
    #pragma unroll
    for (int j = 0; j < 4; ++j)
        #pragma unroll
        for (int r = 0; r < 4; ++r) {
            float vy = y[j][r];
            lsum += vy; lsq += vy * vy;
        }
    #pragma unroll
    for (int m = 32; m; m >>= 1) {
        lsum += __shfl_xor(lsum, m, 64);
        lsq  += __shfl_xor(lsq,  m, 64);
    }
    if (l == 0) { red[w] = lsum; red[4 + w] = lsq; }

    #pragma unroll
    for (int j = 0; j < 4; ++j)
        #pragma unroll
        for (int r = 0; r < 4; ++r)
            tr[j * 16 + lr][16 * w + g * 4 + r] = y[j][r];
    __syncthreads();

    if (tid == 0) {
        float* ps = psums + ((size_t)bh * 32 + c) * 2;
        ps[0] = red[0] + red[1] + red[2] + red[3];
        ps[1] = red[4] + red[5] + red[6] + red[7];
    }

    #pragma unroll
    for (int u = 0; u < 4; ++u) {
        int row  = (tid >> 4) + u * 16;
        int col4 = (tid & 15) * 4;
        v4f val = *(const v4f*)&tr[row][col4];
        v4s pk;
        #pragma unroll
        for (int r = 0; r < 4; ++r) pk[r] = f2bf(val[r]);
        *(v4s*)&Ybf[(size_t)(b * TSEQ + 64 * c + row) * DM + h * 64 + col4] = pk;
    }
}

// ---------------------------------------------------------------------------
// GroupNorm finalize: per (b, channel) scale/shift from chunk partials
// ---------------------------------------------------------------------------
__global__ __launch_bounds__(256) void gn_finalize(
    const float* __restrict__ psums,
    const float* __restrict__ gnw, const float* __restrict__ gnb,
    float* __restrict__ scale, float* __restrict__ shift)
{
    int idx = blockIdx.x * 256 + threadIdx.x;
    if (idx >= NB * DM) return;
    int bb = idx >> 10;
    int ch = idx & (DM - 1);
    int hh = ch >> 6;
    int bh = bb * 16 + hh;

    float s = 0.f, q = 0.f;
    #pragma unroll
    for (int k = 0; k < 32; ++k) {
        s += psums[((size_t)bh * 32 + k) * 2];
        q += psums[((size_t)bh * 32 + k) * 2 + 1];
    }
    const float n = (float)(DH * TSEQ);
    float mean = s / n;
    float var  = q / n - mean * mean;
    float rstd = rsqrtf(var + GN_EPS);
    float sc = rstd * gnw[ch];
    scale[idx] = sc;
    shift[idx] = gnb[ch] - mean * sc;
}

// ---------------------------------------------------------------------------
// wo_prep: Wo2[b][n][k] = bf16(Wo[n][k] * scale[b][k]);
//          bias[b][n]   = sum_k shift[b][k] * Wo[n][k].
// ---------------------------------------------------------------------------
__global__ __launch_bounds__(256) void wo_prep(
    const short* __restrict__ Wob, const float* __restrict__ scale,
    const float* __restrict__ shift,
    short* __restrict__ Wo2, float* __restrict__ bias)
{
    const int tid = threadIdx.x, l = tid & 63, w = tid >> 6;
    const int bn = blockIdx.x * 4 + w;        // 0..2047
    const int b = bn >> 10, n = bn & 1023;
    const int k0 = l * 16;

    const short* wp = Wob + (size_t)n * DM + k0;
    v8s w0 = *(const v8s*)wp;
    v8s w1 = *(const v8s*)(wp + 8);
    const float* sc = scale + b * DM + k0;
    const float* sh = shift + b * DM + k0;

    v8s o0, o1;
    float bsum = 0.f;
    #pragma unroll
    for (int j = 0; j < 8; ++j) {
        float wf = bf2f(w0[j]);
        o0[j] = f2bf(wf * sc[j]);
        bsum = fmaf(sh[j], wf, bsum);
    }
    #pragma unroll
    for (int j = 0; j < 8; ++j) {
        float wf = bf2f(w1[j]);
        o1[j] = f2bf(wf * sc[8 + j]);
        bsum = fmaf(sh[8 + j], wf, bsum);
    }
    short* op = Wo2 + ((size_t)b * DM + n) * DM + k0;
    *(v8s*)op = o0;
    *(v8s*)(op + 8) = o1;

    #pragma unroll
    for (int m = 32; m; m >>= 1) bsum += __shfl_xor(bsum, m, 64);
    if (l == 0) bias[bn] = bsum;
}

// ---------------------------------------------------------------------------
// Output projection: out = Ybf @ Wo2[b]^T + bias[b], fp32 out.  SWAPPED
// fragment -> 16 packed v4f stores.  dbuf loop (1 block/CU -> ILP wins).
// grid 256 1D, XCD-chunked swizzle.
// ---------------------------------------------------------------------------
__global__ __launch_bounds__(256, 2) void gemm_out_mfma(
    const short* __restrict__ Ybf, const short* __restrict__ Wo2,
    const float* __restrict__ bias, float* __restrict__ out)
{
    const int bid = blockIdx.x;
    const int swizb = (bid & 7) * 32 + (bid >> 3);
    const int n0 = (swizb & 7) * 128, m0 = (swizb >> 3) * 128;
    const int b = m0 >> 11;
    const int t = threadIdx.x, l = t & 63, w = t >> 6;
    const int wr = (w >> 1) * 64, wc = (w & 1) * 64;
    const int lr = l & 15, g = l >> 4;

    __shared__ char lds[65536];

    v4f acc[4][4];
    #pragma unroll
    for (int i = 0; i < 4; ++i)
        #pragma unroll
        for (int j = 0; j < 4; ++j) acc[i][j] = (v4f){0.f, 0.f, 0.f, 0.f};

    const char* Agp = (const char*)(Ybf + (size_t)m0 * DM);
    const char* Bgp = (const char*)(Wo2 + (size_t)b * DM * DM + (size_t)n0 * DM);

    mm_loop_db<true>(Agp, Bgp, lds, t, lr, g, wr, wc, acc);

    #pragma unroll
    for (int i = 0; i < 4; ++i) {
        int mrow = m0 + wr + i * 16 + lr;
        #pragma unroll
        for (int j = 0; j < 4; ++j) {
            int ncol = n0 + wc + j * 16 + g * 4;
            v4f bv = *(const v4f*)&bias[b * DM + ncol];
            v4f o = acc[i][j] + bv;
            *(v4f*)&out[(size_t)mrow * DM + ncol] = o;
        }
    }
}

// ---------------------------------------------------------------------------
extern "C" void kernel_launch(void* const* d_in, const int* in_sizes, int n_in,
                              void* d_out, int out_size, void* d_ws, size_t ws_size,
                              hipStream_t stream)
{
    const float* x   = (const float*)d_in[0];
    const float* Wq  = (const float*)d_in[1];
    const float* Wk  = (const float*)d_in[2];
    const float* Wv  = (const float*)d_in[3];
    const float* Wo  = (const float*)d_in[4];
    const float* gnw = (const float*)d_in[5];
    const float* gnb = (const float*)d_in[6];
    float* out = (float*)d_out;

    char* wsb = (char*)d_ws;
    size_t o = 0;
    short* Qb   = (short*)(wsb + o); o += (size_t)NB * TSEQ * DM * 2;   // 8 MiB
    short* Kb   = (short*)(wsb + o); o += (size_t)NB * TSEQ * DM * 2;
    short* Kt   = (short*)(wsb + o); o += (size_t)NB * TSEQ * DM * 2;
    short* Vt   = (short*)(wsb + o); o += (size_t)NB * TSEQ * DM * 2;
    short* xbf  = (short*)(wsb + o); o += (size_t)NB * TSEQ * DM * 2;
    short* wbf  = (short*)(wsb + o); o += (size_t)4 * DM * DM * 2;      // 8 MiB
    short* Ybf  = (short*)(wsb + o); o += (size_t)NB * TSEQ * DM * 2;
    short* St   = (short*)(wsb + o); o += (size_t)NB * TSEQ * DM * 2;   // 8 MiB
    short* Wo2  = (short*)(wsb + o); o += (size_t)NB * DM * DM * 2;     // 4 MiB
    float* psums = (float*)(wsb + o); o += (size_t)32 * 32 * 2 * 4;
    float* scale = (float*)(wsb + o); o += (size_t)NB * DM * 4;
    float* shift = (float*)(wsb + o); o += (size_t)NB * DM * 4;
    float* bias  = (float*)(wsb + o); o += (size_t)NB * DM * 4;
    if (ws_size < o) return;

    short* At = xbf;   // alias (stream-ordered): xbf dead after gemm_qkv

    cast_kernel<<<2048, 256, 0, stream>>>(x, Wq, Wk, Wv, Wo, xbf, wbf);
    gemm_qkv_fused<<<dim3(1024), 256, 0, stream>>>(xbf, wbf, Qb, Kb, Kt, Vt);
    chunk_kv<<<dim3(1024), 256, 0, stream>>>(Kt, Vt, At);
    chunk_scan<<<dim3(512), 256, 0, stream>>>(At, St);
    chunk_out<<<dim3(1024), 256, 0, stream>>>(Qb, Kb, Vt, St, Ybf, psums);
    gn_finalize<<<dim3((NB * DM + 255) / 256), 256, 0, stream>>>(
        psums, gnw, gnb, scale, shift);
    wo_prep<<<dim3(512), 256, 0, stream>>>(
        wbf + 3 * (size_t)DM * DM, scale, shift, Wo2, bias);
    gemm_out_mfma<<<dim3(256), 256, 0, stream>>>(Ybf, Wo2, bias, out);
}

// Round 21
// 86.830 us; speedup vs baseline: 1.0365x; 1.0365x over previous
//
#include <hip/hip_runtime.h>
#include <math.h>

#define TSEQ 2048
#define NB   2
#define DM   1024
#define NH   16
#define DH   64
#define GN_EPS 1e-5f

typedef short v8s __attribute__((ext_vector_type(8)));
typedef short v4s __attribute__((ext_vector_type(4)));
typedef float v4f __attribute__((ext_vector_type(4)));

__device__ __forceinline__ short f2bf(float f) {
    union { float f; unsigned u; } c; c.f = f;
    unsigned u = c.u;
    unsigned r = (u + 0x7fffu + ((u >> 16) & 1u)) >> 16;   // RNE
    return (short)r;
}
__device__ __forceinline__ float bf2f(short s) {
    union { unsigned u; float f; } c; c.u = ((unsigned)(unsigned short)s) << 16;
    return c.f;
}

// pack two f32 -> two bf16 in one instruction (no builtin on gfx950)
__device__ __forceinline__ unsigned cvtpk_bf16(float lo, float hi) {
    unsigned r;
    asm("v_cvt_pk_bf16_f32 %0, %1, %2" : "=v"(r) : "v"(lo), "v"(hi));
    return r;
}

// async global->LDS, 16B per lane.  LDS dest = wave-uniform base + lane*16.
__device__ __forceinline__ void gl_lds16(const void* g, void* l) {
    __builtin_amdgcn_global_load_lds(
        (const __attribute__((address_space(1))) void*)g,
        (__attribute__((address_space(3))) void*)l, 16, 0, 0);
}

// ---------------------------------------------------------------------------
// cast x and the 4 weight matrices to bf16
// ---------------------------------------------------------------------------
__global__ __launch_bounds__(256) void cast_kernel(
    const float* __restrict__ x,
    const float* __restrict__ Wq, const float* __restrict__ Wk,
    const float* __restrict__ Wv, const float* __restrict__ Wo,
    short* __restrict__ xbf, short* __restrict__ wbf)
{
    const int NX = NB * TSEQ * DM;            // 4,194,304
    const int NW = DM * DM;                   // 1,048,576
    const int total4 = (NX + 4 * NW) / 4;     // 2,097,152
    for (int i = blockIdx.x * 256 + threadIdx.x; i < total4;
         i += gridDim.x * 256) {
        int e = i * 4;
        const float* src; short* dst;
        if (e < NX) { src = x + e; dst = xbf + e; }
        else {
            int o = e - NX;
            int w = o >> 20;
            int r = o & (NW - 1);
            src = (w == 0 ? Wq : w == 1 ? Wk : w == 2 ? Wv : Wo) + r;
            dst = wbf + o;
        }
        v4f v = *(const v4f*)src;
        v4s s;
        #pragma unroll
        for (int j = 0; j < 4; ++j) s[j] = f2bf(v[j]);
        *(v4s*)dst = s;
    }
}

// ---------------------------------------------------------------------------
// FUSED QKV projection, DOUBLE-BUFFERED: 128m x 64n tile, BK=64.  LDS =
// 2 x (A 16KB + 3xB 8KB) = 80 KB -> still 2 blocks/CU (no occupancy cost,
// R16 lesson: dbuf is pure profit when blocks/CU is unchanged).  Per iter:
// vmcnt(0) drains loads issued a FULL compute phase ago, ONE barrier, issue
// tile t+1 into the idle half, then 48 MFMA/wave (A reused 3x).  grid 512,
// XCD swizzle 8m x 8n sub-block.  BN=64 = one head -> l2g block-uniform.
// Q uses SWAPPED operands (packed row-major stores); K/V normal.
// ---------------------------------------------------------------------------
__global__ __launch_bounds__(256, 2) void gemm_qkv_fused(
    const short* __restrict__ xbf, const short* __restrict__ wbf,
    short* __restrict__ Qb, short* __restrict__ Kb,
    short* __restrict__ Kt, short* __restrict__ Vt)
{
    const int bid = blockIdx.x;                 // 0..511
    const int xcd = bid & 7, ch = bid >> 3;     // 64 blocks per XCD
    const int sm = xcd >> 1, sn = xcd & 1;
    const int m0 = (sm * 8 + (ch >> 3)) * 128;  // 32 m-tiles
    const int n0 = (sn * 8 + (ch & 7)) * 64;    // 16 n-tiles (one head each)

    const int t = threadIdx.x, l = t & 63, w = t >> 6;
    const int wm = (w >> 1) * 64, wn = (w & 1) * 32;
    const int lr = l & 15, g = l >> 4;
    const int swz = (lr & 7) << 4;

    __shared__ char lds[81920];                 // 2 x 40 KB halves

    v4f acc[3][4][2];
    #pragma unroll
    for (int z = 0; z < 3; ++z)
        #pragma unroll
        for (int i = 0; i < 4; ++i)
            #pragma unroll
            for (int j = 0; j < 2; ++j) acc[z][i][j] = (v4f){0.f,0.f,0.f,0.f};

    const char* Agp = (const char*)(xbf + (size_t)m0 * DM);
    const char* Bgp = (const char*)(wbf + (size_t)n0 * DM);
    const size_t ZS = (size_t)DM * DM * 2;      // 2 MiB per weight matrix

    int soffA[4], sdstA[4], soffB[2], sdstB[2];
    #pragma unroll
    for (int p = 0; p < 4; ++p) {
        int c = p * 256 + t;
        int row = c >> 3, u = c & 7;
        soffA[p] = row * (DM * 2) + ((u * 16) ^ ((row & 7) << 4));
        sdstA[p] = (p * 256 + (t & 192)) * 16;
    }
    #pragma unroll
    for (int p = 0; p < 2; ++p) {
        int c = p * 256 + t;
        int row = c >> 3, u = c & 7;
        soffB[p] = row * (DM * 2) + ((u * 16) ^ ((row & 7) << 4));
        sdstB[p] = (p * 256 + (t & 192)) * 16;
    }

#define STAGE(tt) { \
    char* base_ = lds + ((tt) & 1) * 40960; \
    const size_t kb_ = (size_t)(tt) * 128; \
    _Pragma("unroll") \
    for (int p = 0; p < 4; ++p) \
        gl_lds16(Agp + (size_t)soffA[p] + kb_, base_ + sdstA[p]); \
    _Pragma("unroll") \
    for (int z = 0; z < 3; ++z) \
        _Pragma("unroll") \
        for (int p = 0; p < 2; ++p) \
            gl_lds16(Bgp + ZS * z + (size_t)soffB[p] + kb_, \
                     base_ + 16384 + z * 8192 + sdstB[p]); }

    STAGE(0);

    for (int kt = 0; kt < DM / 64; ++kt) {
        const char* cur = lds + (kt & 1) * 40960;
        asm volatile("s_waitcnt vmcnt(0)" ::: "memory");
        __syncthreads();

        if (kt < DM / 64 - 1) STAGE(kt + 1);

        v8s af[4][2];
        #pragma unroll
        for (int i = 0; i < 4; ++i) {
            int rowa = wm + i * 16 + lr;
            af[i][0] = *(const v8s*)(cur + rowa * 128 + ((g * 16) ^ swz));
            af[i][1] = *(const v8s*)(cur + rowa * 128 + ((64 + g * 16) ^ swz));
        }
        #pragma unroll
        for (int z = 0; z < 3; ++z) {
            const char* Bz = cur + 16384 + z * 8192;
            #pragma unroll
            for (int j = 0; j < 2; ++j) {
                int rowb = wn + j * 16 + lr;
                v8s b0 = *(const v8s*)(Bz + rowb * 128 + ((g * 16) ^ swz));
                v8s b1 = *(const v8s*)(Bz + rowb * 128 + ((64 + g * 16) ^ swz));
                #pragma unroll
                for (int i = 0; i < 4; ++i) {
                    if (z == 0) {   // Q: swapped -> transposed fragment
                        acc[0][i][j] = __builtin_amdgcn_mfma_f32_16x16x32_bf16(
                            b0, af[i][0], acc[0][i][j], 0, 0, 0);
                        acc[0][i][j] = __builtin_amdgcn_mfma_f32_16x16x32_bf16(
                            b1, af[i][1], acc[0][i][j], 0, 0, 0);
                    } else {
                        acc[z][i][j] = __builtin_amdgcn_mfma_f32_16x16x32_bf16(
                            af[i][0], b0, acc[z][i][j], 0, 0, 0);
                        acc[z][i][j] = __builtin_amdgcn_mfma_f32_16x16x32_bf16(
                            af[i][1], b1, acc[z][i][j], 0, 0, 0);
                    }
                }
            }
        }
    }
#undef STAGE

    // ---------------- epilogues (one head: l2g block-uniform) ----------------
    const int head = n0 >> 6;
    const float l2g = log2f(1.0f - exp2f(-5.0f - (float)head));

    // Q: packed v4s row-major stores, 4 exp2/thread
    {
        float fac[4];
        #pragma unroll
        for (int i = 0; i < 4; ++i) {
            int tl = (m0 + wm + i * 16 + lr) & 63;
            fac[i] = exp2f(fmaf(l2g, (float)tl, -3.0f));   // gamma^tl / 8
        }
        #pragma unroll
        for (int i = 0; i < 4; ++i) {
            int mrow = m0 + wm + i * 16 + lr;
            #pragma unroll
            for (int j = 0; j < 2; ++j) {
                int ncol = n0 + wn + j * 16 + g * 4;
                v4s pk;
                #pragma unroll
                for (int r = 0; r < 4; ++r) pk[r] = f2bf(acc[0][i][j][r] * fac[i]);
                *(v4s*)(Qb + (size_t)mrow * DM + ncol) = pk;
            }
        }
    }
    // K: Kb row-major scalar + Kt transposed packed
    {
        const float l2gk = -l2g;
        #pragma unroll
        for (int i = 0; i < 4; ++i) {
            int row  = m0 + wm + i * 16 + g * 4;
            int bidx = row >> 11, tb = row & (TSEQ - 1);
            #pragma unroll
            for (int j = 0; j < 2; ++j) {
                int col = n0 + wn + j * 16 + lr;
                v4s pk;
                #pragma unroll
                for (int r = 0; r < 4; ++r) {
                    int tl = (row + r) & 63;
                    float fc = exp2f(l2gk * (float)tl);
                    short bv = f2bf(acc[1][i][j][r] * fc);
                    Kb[(size_t)(row + r) * DM + col] = bv;
                    pk[r] = bv;
                }
                *(v4s*)(Kt + ((size_t)bidx << 21) + ((size_t)col << 11) + tb) = pk;
            }
        }
    }
    // V: Vt transposed packed
    {
        #pragma unroll
        for (int i = 0; i < 4; ++i) {
            int row  = m0 + wm + i * 16 + g * 4;
            int bidx = row >> 11, tb = row & (TSEQ - 1);
            #pragma unroll
            for (int j = 0; j < 2; ++j) {
                int col = n0 + wn + j * 16 + lr;
                v4s pk;
                #pragma unroll
                for (int r = 0; r < 4; ++r) pk[r] = f2bf(acc[2][i][j][r]);
                *(v4s*)(Vt + ((size_t)bidx << 21) + ((size_t)col << 11) + tb) = pk;
            }
        }
    }
}

// ---------------------------------------------------------------------------
// Double-buffered staged 128x128 loop (64 KB LDS) — for the 1-block/CU
// out-GEMM where there is no TLP to lose.  SWAP=true -> transposed fragment.
// ---------------------------------------------------------------------------
template <bool SWAP>
__device__ __forceinline__ void mm_loop_db(
    const char* Agp, const char* Bgp, char* lds,
    int t, int lr, int g, int wr, int wc, v4f acc[4][4])
{
    int soff[4], sdst[4];
    #pragma unroll
    for (int p = 0; p < 4; ++p) {
        int i = p * 256 + t;
        int row = i >> 3;
        int cp  = (i & 7) * 16;
        soff[p] = row * (DM * 2) + (cp ^ ((row & 7) << 4));
        sdst[p] = (p * 256 + (t & 192)) * 16;      // wave-uniform base
    }
    const int swz = (lr & 7) << 4;

    #pragma unroll
    for (int p = 0; p < 4; ++p) {
        gl_lds16(Agp + (size_t)soff[p], lds + sdst[p]);
        gl_lds16(Bgp + (size_t)soff[p], lds + 16384 + sdst[p]);
    }

    for (int kt = 0; kt < DM / 64; ++kt) {
        const char* cur = lds + (kt & 1) * 32768;
        asm volatile("s_waitcnt vmcnt(0)" ::: "memory");
        __syncthreads();

        if (kt < DM / 64 - 1) {
            char* nxt = lds + ((kt + 1) & 1) * 32768;
            const int kb = (kt + 1) * 128;
            #pragma unroll
            for (int p = 0; p < 4; ++p) {
                gl_lds16(Agp + (size_t)soff[p] + kb, nxt + sdst[p]);
                gl_lds16(Bgp + (size_t)soff[p] + kb, nxt + 16384 + sdst[p]);
            }
        }

        v8s bfr[4][2];
        #pragma unroll
        for (int j = 0; j < 4; ++j) {
            int rowb = wc + j * 16 + lr;
            #pragma unroll
            for (int ks = 0; ks < 2; ++ks)
                bfr[j][ks] = *(const v8s*)(cur + 16384 + rowb * 128
                               + ((ks * 64 + g * 16) ^ swz));
        }
        #pragma unroll
        for (int i = 0; i < 4; ++i) {
            int rowa = wr + i * 16 + lr;
            v8s a0 = *(const v8s*)(cur + rowa * 128 + ((g * 16) ^ swz));
            v8s a1 = *(const v8s*)(cur + rowa * 128 + ((64 + g * 16) ^ swz));
            #pragma unroll
            for (int j = 0; j < 4; ++j) {
                if (SWAP) {
                    acc[i][j] = __builtin_amdgcn_mfma_f32_16x16x32_bf16(
                        bfr[j][0], a0, acc[i][j], 0, 0, 0);
                    acc[i][j] = __builtin_amdgcn_mfma_f32_16x16x32_bf16(
                        bfr[j][1], a1, acc[i][j], 0, 0, 0);
                } else {
                    acc[i][j] = __builtin_amdgcn_mfma_f32_16x16x32_bf16(
                        a0, bfr[j][0], acc[i][j], 0, 0, 0);
                    acc[i][j] = __builtin_amdgcn_mfma_f32_16x16x32_bf16(
                        a1, bfr[j][1], acc[i][j], 0, 0, 0);
                }
            }
        }
    }
}

// ---------------------------------------------------------------------------
// chunk_kv: per (b,h,chunk) compute A_c^T[dv][dk] = sum_jl V[jl][dv]*K'[jl][dk]
// ---------------------------------------------------------------------------
__global__ __launch_bounds__(256, 2) void chunk_kv(
    const short* __restrict__ Kt, const short* __restrict__ Vt,
    short* __restrict__ At)
{
    const int bid = blockIdx.x;                // 1024
    const int c = bid & 31, bh = bid >> 5;
    const int b = bh >> 4, h = bh & 15;
    const int tid = threadIdx.x, l = tid & 63, w = tid >> 6;
    const int lr = l & 15, g = l >> 4;

    const size_t rowbase = ((size_t)b * DM + h * 64);

    v8s kf[2], vf[4][2];
    {
        const short* kp = Kt + (rowbase + 16 * w + lr) * TSEQ + 64 * c;
        kf[0] = *(const v8s*)(kp + g * 8);
        kf[1] = *(const v8s*)(kp + 32 + g * 8);
    }
    #pragma unroll
    for (int j = 0; j < 4; ++j) {
        const short* vp = Vt + (rowbase + j * 16 + lr) * TSEQ + 64 * c;
        vf[j][0] = *(const v8s*)(vp + g * 8);
        vf[j][1] = *(const v8s*)(vp + 32 + g * 8);
    }

    v4f acc[4];
    #pragma unroll
    for (int j = 0; j < 4; ++j) acc[j] = (v4f){0.f, 0.f, 0.f, 0.f};

    #pragma unroll
    for (int j = 0; j < 4; ++j) {
        acc[j] = __builtin_amdgcn_mfma_f32_16x16x32_bf16(kf[0], vf[j][0], acc[j], 0, 0, 0);
        acc[j] = __builtin_amdgcn_mfma_f32_16x16x32_bf16(kf[1], vf[j][1], acc[j], 0, 0, 0);
    }

    short* Ab = At + (((size_t)bh * 32 + c) << 12);
    #pragma unroll
    for (int j = 0; j < 4; ++j) {
        v4s pk;
        #pragma unroll
        for (int r = 0; r < 4; ++r) pk[r] = f2bf(acc[j][r]);
        *(v4s*)(Ab + (j * 16 + lr) * 64 + 16 * w + g * 4) = pk;
    }
}

// ---------------------------------------------------------------------------
// chunk_scan: State_c = gamma^64 * (State_{c-1} + A_{c-1})
// ---------------------------------------------------------------------------
__global__ __launch_bounds__(256) void chunk_scan(
    const short* __restrict__ At, short* __restrict__ St)
{
    const int idx = blockIdx.x * 256 + threadIdx.x;   // 131072
    const int bh = idx >> 12;
    const int h  = bh & 15;
    const float l2g = log2f(1.0f - exp2f(-5.0f - (float)h));
    const float g64 = exp2f(l2g * 64.0f);

    const size_t base = ((size_t)bh << 17) + (idx & 4095);
    float state = 0.0f;
    #pragma unroll
    for (int c = 1; c < 32; ++c) {
        float a = bf2f(At[base + ((size_t)(c - 1) << 12)]);
        state = g64 * (state + a);
        St[base + ((size_t)c << 12)] = f2bf(state);
    }
}

// ---------------------------------------------------------------------------
// chunk_out: Y_c^T = StateT_c.Q'^T + V^T.(mask(Q'K'^T)); writes UN-NORMALIZED
// Ybf (bf16).  GN partials -> plain stores to psums (no atomics).
// ---------------------------------------------------------------------------
__global__ __launch_bounds__(256, 2) void chunk_out(
    const short* __restrict__ Qb, const short* __restrict__ Kb,
    const short* __restrict__ Vt, const short* __restrict__ St,
    short* __restrict__ Ybf, float* __restrict__ psums)
{
    const int bid = blockIdx.x;                 // 1024
    const int xcd = bid & 7, r8 = bid >> 3;
    const int bh  = xcd * 4 + (r8 >> 5);
    const int c   = r8 & 31;
    const int b = bh >> 4, h = bh & 15;
    const int tid = threadIdx.x, l = tid & 63, w = tid >> 6;
    const int lr = l & 15, g = l >> 4;

    __shared__ short strip[64 * 64];
    __shared__ float tr[64][68];
    __shared__ float red[8];

    const size_t rowQK = ((size_t)(b * TSEQ + 64 * c)) * DM + h * 64;

    v8s qf[4][2];
    #pragma unroll
    for (int j = 0; j < 4; ++j) {
        const short* qp = Qb + rowQK + (size_t)(j * 16 + lr) * DM;
        qf[j][0] = *(const v8s*)(qp + g * 8);
        qf[j][1] = *(const v8s*)(qp + 32 + g * 8);
    }
    v8s kf0, kf1;
    {
        const short* kp = Kb + rowQK + (size_t)(16 * w + lr) * DM;
        kf0 = *(const v8s*)(kp + g * 8);
        kf1 = *(const v8s*)(kp + 32 + g * 8);
    }
    v8s sf0 = {}, sf1 = {};
    if (c > 0) {
        const short* sp = St + (((size_t)bh * 32 + c) << 12) + (16 * w + lr) * 64;
        sf0 = *(const v8s*)(sp + g * 8);
        sf1 = *(const v8s*)(sp + 32 + g * 8);
    }
    v8s vf0, vf1;
    {
        const short* vp = Vt + ((size_t)(b * DM + h * 64) + 16 * w + lr) * TSEQ
                          + 64 * c;
        vf0 = *(const v8s*)(vp + g * 8);
        vf1 = *(const v8s*)(vp + 32 + g * 8);
    }

    v4f s[4];
    #pragma unroll
    for (int j = 0; j < 4; ++j) {
        v4f a = (v4f){0.f, 0.f, 0.f, 0.f};
        a = __builtin_amdgcn_mfma_f32_16x16x32_bf16(kf0, qf[j][0], a, 0, 0, 0);
        a = __builtin_amdgcn_mfma_f32_16x16x32_bf16(kf1, qf[j][1], a, 0, 0, 0);
        s[j] = a;
    }

    v4f y[4];
    #pragma unroll
    for (int j = 0; j < 4; ++j) y[j] = (v4f){0.f, 0.f, 0.f, 0.f};
    if (c > 0) {
        #pragma unroll
        for (int j = 0; j < 4; ++j) {
            y[j] = __builtin_amdgcn_mfma_f32_16x16x32_bf16(sf0, qf[j][0], y[j], 0, 0, 0);
            y[j] = __builtin_amdgcn_mfma_f32_16x16x32_bf16(sf1, qf[j][1], y[j], 0, 0, 0);
        }
    }

    #pragma unroll
    for (int j = 0; j < 4; ++j) {
        v4f vv = s[j];
        #pragma unroll
        for (int r = 0; r < 4; ++r)
            if ((j * 16 + lr) - (16 * w + g * 4 + r) < 0) vv[r] = 0.0f;
        unsigned u0 = cvtpk_bf16(vv[0], vv[1]);
        unsigned u1 = cvtpk_bf16(vv[2], vv[3]);
        int byte = ((j * 16 + lr) * 128 + 32 * w + g * 8) ^ ((lr & 7) << 4);
        *(unsigned long long*)((char*)strip + byte) =
            (unsigned long long)u0 | ((unsigned long long)u1 << 32);
    }
    __syncthreads();

    #pragma unroll
    for (int j = 0; j < 4; ++j) {
        int rb = (j * 16 + lr) * 128;
        int sw = (lr & 7) << 4;
        v8s sB0 = *(const v8s*)((char*)strip + ((rb + g * 16) ^ sw));
        v8s sB1 = *(const v8s*)((char*)strip + ((rb + 64 + g * 16) ^ sw));
        y[j] = __builtin_amdgcn_mfma_f32_16x16x32_bf16(vf0, sB0, y[j], 0, 0, 0);
        y[j] = __builtin_amdgcn_mfma_f32_16x16x32_bf16(vf1, sB1, y[j], 0, 0, 0);
    }

    float lsum = 0.f, lsq = 0.f;
    #pragma unroll
    for (int j = 0; j < 4; ++j)
        #pragma unroll
        for (int r = 0; r < 4; ++r) {
            float vy = y[j][r];
            lsum += vy; lsq += vy * vy;
        }
    #pragma unroll
    for (int m = 32; m; m >>= 1) {
        lsum += __shfl_xor(lsum, m, 64);
        lsq  += __shfl_xor(lsq,  m, 64);
    }
    if (l == 0) { red[w] = lsum; red[4 + w] = lsq; }

    #pragma unroll
    for (int j = 0; j < 4; ++j)
        #pragma unroll
        for (int r = 0; r < 4; ++r)
            tr[j * 16 + lr][16 * w + g * 4 + r] = y[j][r];
    __syncthreads();

    if (tid == 0) {
        float* ps = psums + ((size_t)bh * 32 + c) * 2;
        ps[0] = red[0] + red[1] + red[2] + red[3];
        ps[1] = red[4] + red[5] + red[6] + red[7];
    }

    #pragma unroll
    for (int u = 0; u < 4; ++u) {
        int row  = (tid >> 4) + u * 16;
        int col4 = (tid & 15) * 4;
        v4f val = *(const v4f*)&tr[row][col4];
        v4s pk;
        #pragma unroll
        for (int r = 0; r < 4; ++r) pk[r] = f2bf(val[r]);
        *(v4s*)&Ybf[(size_t)(b * TSEQ + 64 * c + row) * DM + h * 64 + col4] = pk;
    }
}

// ---------------------------------------------------------------------------
// GroupNorm finalize: per (b, channel) scale/shift from chunk partials
// ---------------------------------------------------------------------------
__global__ __launch_bounds__(256) void gn_finalize(
    const float* __restrict__ psums,
    const float* __restrict__ gnw, const float* __restrict__ gnb,
    float* __restrict__ scale, float* __restrict__ shift)
{
    int idx = blockIdx.x * 256 + threadIdx.x;
    if (idx >= NB * DM) return;
    int bb = idx >> 10;
    int ch = idx & (DM - 1);
    int hh = ch >> 6;
    int bh = bb * 16 + hh;

    float s = 0.f, q = 0.f;
    #pragma unroll
    for (int k = 0; k < 32; ++k) {
        s += psums[((size_t)bh * 32 + k) * 2];
        q += psums[((size_t)bh * 32 + k) * 2 + 1];
    }
    const float n = (float)(DH * TSEQ);
    float mean = s / n;
    float var  = q / n - mean * mean;
    float rstd = rsqrtf(var + GN_EPS);
    float sc = rstd * gnw[ch];
    scale[idx] = sc;
    shift[idx] = gnb[ch] - mean * sc;
}

// ---------------------------------------------------------------------------
// wo_prep: Wo2[b][n][k] = bf16(Wo[n][k] * scale[b][k]);
//          bias[b][n]   = sum_k shift[b][k] * Wo[n][k].
// ---------------------------------------------------------------------------
__global__ __launch_bounds__(256) void wo_prep(
    const short* __restrict__ Wob, const float* __restrict__ scale,
    const float* __restrict__ shift,
    short* __restrict__ Wo2, float* __restrict__ bias)
{
    const int tid = threadIdx.x, l = tid & 63, w = tid >> 6;
    const int bn = blockIdx.x * 4 + w;        // 0..2047
    const int b = bn >> 10, n = bn & 1023;
    const int k0 = l * 16;

    const short* wp = Wob + (size_t)n * DM + k0;
    v8s w0 = *(const v8s*)wp;
    v8s w1 = *(const v8s*)(wp + 8);
    const float* sc = scale + b * DM + k0;
    const float* sh = shift + b * DM + k0;

    v8s o0, o1;
    float bsum = 0.f;
    #pragma unroll
    for (int j = 0; j < 8; ++j) {
        float wf = bf2f(w0[j]);
        o0[j] = f2bf(wf * sc[j]);
        bsum = fmaf(sh[j], wf, bsum);
    }
    #pragma unroll
    for (int j = 0; j < 8; ++j) {
        float wf = bf2f(w1[j]);
        o1[j] = f2bf(wf * sc[8 + j]);
        bsum = fmaf(sh[8 + j], wf, bsum);
    }
    short* op = Wo2 + ((size_t)b * DM + n) * DM + k0;
    *(v8s*)op = o0;
    *(v8s*)(op + 8) = o1;

    #pragma unroll
    for (int m = 32; m; m >>= 1) bsum += __shfl_xor(bsum, m, 64);
    if (l == 0) bias[bn] = bsum;
}

// ---------------------------------------------------------------------------
// Output projection: out = Ybf @ Wo2[b]^T + bias[b], fp32 out.  SWAPPED
// fragment -> 16 packed v4f stores.  dbuf loop (1 block/CU -> ILP wins).
// grid 256 1D, XCD-chunked swizzle.
// ---------------------------------------------------------------------------
__global__ __launch_bounds__(256, 2) void gemm_out_mfma(
    const short* __restrict__ Ybf, const short* __restrict__ Wo2,
    const float* __restrict__ bias, float* __restrict__ out)
{
    const int bid = blockIdx.x;
    const int swizb = (bid & 7) * 32 + (bid >> 3);
    const int n0 = (swizb & 7) * 128, m0 = (swizb >> 3) * 128;
    const int b = m0 >> 11;
    const int t = threadIdx.x, l = t & 63, w = t >> 6;
    const int wr = (w >> 1) * 64, wc = (w & 1) * 64;
    const int lr = l & 15, g = l >> 4;

    __shared__ char lds[65536];

    v4f acc[4][4];
    #pragma unroll
    for (int i = 0; i < 4; ++i)
        #pragma unroll
        for (int j = 0; j < 4; ++j) acc[i][j] = (v4f){0.f, 0.f, 0.f, 0.f};

    const char* Agp = (const char*)(Ybf + (size_t)m0 * DM);
    const char* Bgp = (const char*)(Wo2 + (size_t)b * DM * DM + (size_t)n0 * DM);

    mm_loop_db<true>(Agp, Bgp, lds, t, lr, g, wr, wc, acc);

    #pragma unroll
    for (int i = 0; i < 4; ++i) {
        int mrow = m0 + wr + i * 16 + lr;
        #pragma unroll
        for (int j = 0; j < 4; ++j) {
            int ncol = n0 + wc + j * 16 + g * 4;
            v4f bv = *(const v4f*)&bias[b * DM + ncol];
            v4f o = acc[i][j] + bv;
            *(v4f*)&out[(size_t)mrow * DM + ncol] = o;
        }
    }
}

// ---------------------------------------------------------------------------
extern "C" void kernel_launch(void* const* d_in, const int* in_sizes, int n_in,
                              void* d_out, int out_size, void* d_ws, size_t ws_size,
                              hipStream_t stream)
{
    const float* x   = (const float*)d_in[0];
    const float* Wq  = (const float*)d_in[1];
    const float* Wk  = (const float*)d_in[2];
    const float* Wv  = (const float*)d_in[3];
    const float* Wo  = (const float*)d_in[4];
    const float* gnw = (const float*)d_in[5];
    const float* gnb = (const float*)d_in[6];
    float* out = (float*)d_out;

    char* wsb = (char*)d_ws;
    size_t o = 0;
    short* Qb   = (short*)(wsb + o); o += (size_t)NB * TSEQ * DM * 2;   // 8 MiB
    short* Kb   = (short*)(wsb + o); o += (size_t)NB * TSEQ * DM * 2;
    short* Kt   = (short*)(wsb + o); o += (size_t)NB * TSEQ * DM * 2;
    short* Vt   = (short*)(wsb + o); o += (size_t)NB * TSEQ * DM * 2;
    short* xbf  = (short*)(wsb + o); o += (size_t)NB * TSEQ * DM * 2;
    short* wbf  = (short*)(wsb + o); o += (size_t)4 * DM * DM * 2;      // 8 MiB
    short* Ybf  = (short*)(wsb + o); o += (size_t)NB * TSEQ * DM * 2;
    short* St   = (short*)(wsb + o); o += (size_t)NB * TSEQ * DM * 2;   // 8 MiB
    short* Wo2  = (short*)(wsb + o); o += (size_t)NB * DM * DM * 2;     // 4 MiB
    float* psums = (float*)(wsb + o); o += (size_t)32 * 32 * 2 * 4;
    float* scale = (float*)(wsb + o); o += (size_t)NB * DM * 4;
    float* shift = (float*)(wsb + o); o += (size_t)NB * DM * 4;
    float* bias  = (float*)(wsb + o); o += (size_t)NB * DM * 4;
    if (ws_size < o) return;

    short* At = xbf;   // alias (stream-ordered): xbf dead after gemm_qkv

    cast_kernel<<<2048, 256, 0, stream>>>(x, Wq, Wk, Wv, Wo, xbf, wbf);
    gemm_qkv_fused<<<dim3(512), 256, 0, stream>>>(xbf, wbf, Qb, Kb, Kt, Vt);
    chunk_kv<<<dim3(1024), 256, 0, stream>>>(Kt, Vt, At);
    chunk_scan<<<dim3(512), 256, 0, stream>>>(At, St);
    chunk_out<<<dim3(1024), 256, 0, stream>>>(Qb, Kb, Vt, St, Ybf, psums);
    gn_finalize<<<dim3((NB * DM + 255) / 256), 256, 0, stream>>>(
        psums, gnw, gnb, scale, shift);
    wo_prep<<<dim3(512), 256, 0, stream>>>(
        wbf + 3 * (size_t)DM * DM, scale, shift, Wo2, bias);
    gemm_out_mfma<<<dim3(256), 256, 0, stream>>>(Ybf, Wo2, bias, out);
}